// Round 3
// baseline (346.600 us; speedup 1.0000x reference)
//
#include <hip/hip_runtime.h>
#include <cstdint>
#include <cstddef>

// Instant-NGP hash-grid encode, R8.
//
// History: R1 fused 247 us (L2 thrash). R5 split: hashed-slices + gather =
// 350.7 us harness (gather 130.5). R6 LDS-transpose + full-line nt stores:
// 326.0 (gather 106). R7 single-phase flush: 325.1 (gather 101.4, occ 39.6%
// vs R6 70% with ~same time -> not occupancy-starved).
//
// Cost model (calibrated R5-R7): ~2.2 cyc/CU per 64B-line transaction on
// the L1/TA path, loads and stores alike; divergent gathers ~1 line/lane.
// NOTE mask kills levels 8-15 (INIT_ACTIVE_LEVEL=8): hashed kernel runs
// only 3 slices (5,6,7) ~= 84 us = its line floor. gather_out line floor
// ~= 80 us (dense 1200 lines/wave + stores 128 + streams) vs 101 measured:
// ~20 us gap = VMEM latency serialization (VGPR=44 -> <=8 loads in flight,
// compiler drains vmcnt mid-loop per level).
//
// R8: MLP-batch restructure. Issue ALL loads first (11 ws v2f + 20 dense
// v4f, unconditional; mask applied in FMA phase -- ws values need a select
// so 0*garbage-NaN can't leak), then all FMAs, then the R7 transpose/store.
// Same batching in hashed kernel (8 gathers then FMAs). Predicts gather
// 101 -> ~85, VGPR -> ~130.

namespace {

constexpr int      kNLevels = 16;
constexpr uint32_t kT       = 1u << 19;             // 524288 entries / level
constexpr uint32_t kP1      = 2654435761u;           // tcnn hash primes (y, z)
constexpr uint32_t kP2      = 805459861u;

typedef float v2f __attribute__((ext_vector_type(2)));
typedef float v4f __attribute__((ext_vector_type(4)));

// floor(16 * scale^lv) + 1, scale = exp((ln 2048 - ln 16)/15)
__device__ constexpr int kRes[kNLevels] = {
    17, 23, 31, 43, 59, 81, 112, 154, 213, 295, 407, 562, 777, 1073, 1483, 2049
};
// dense iff res^3 <= T  <=>  res <= 80; levels 0..4 dense, 5..15 hashed.

__device__ inline void corner_setup(float px, float py, float pz, int res,
                                    int& cx, int& cy, int& cz,
                                    float& wx, float& wy, float& wz) {
    const float s = (float)(res - 1);
    const float fx = px * s, fy = py * s, fz = pz * s;
    cx = (int)floorf(fx); cy = (int)floorf(fy); cz = (int)floorf(fz);
    cx = min(max(cx, 0), res - 2);
    cy = min(max(cy, 0), res - 2);
    cz = min(max(cz, 0), res - 2);
    wx = fx - (float)cx; wy = fy - (float)cy; wz = fz - (float)cz;
}

__device__ inline void load_xyz(const float* __restrict__ x, int p,
                                float& px, float& py, float& pz) {
    float v[3];
    __builtin_memcpy(v, x + 3 * (size_t)p, 12);   // dwordx2 + dword
    px = v[0]; py = v[1]; pz = v[2];
}

// ---------- Phase 1: hashed levels 5..15, one blockIdx.y slice per level ----
__global__ __launch_bounds__(256) void hashed_level_kernel(
    const float* __restrict__ x, const float* __restrict__ table,
    const float* __restrict__ mask, float* __restrict__ ws, int n)
{
    const int lv = 5 + blockIdx.y;
    const float m0 = mask[2 * lv], m1 = mask[2 * lv + 1];
    if (m0 == 0.0f && m1 == 0.0f) return;   // masked level: slice exits

    const int p = blockIdx.x * blockDim.x + threadIdx.x;
    if (p >= n) return;
    float px, py, pz;
    load_xyz(x, p, px, py, pz);

    const int res = kRes[lv];
    int cx, cy, cz; float wx, wy, wz;
    corner_setup(px, py, pz, res, cx, cy, cz, wx, wy, wz);
    const float ux = 1.0f - wx, uy = 1.0f - wy, uz = 1.0f - wz;
    const float* __restrict__ tbl = table + (size_t)lv * (size_t)(kT * 2);

    // hash components (CSE'd): idx = (cx+dx) ^ hy[dy] ^ hz[dz], masked
    const uint32_t hy0 = (uint32_t)cy * kP1, hy1 = (uint32_t)(cy + 1) * kP1;
    const uint32_t hz0 = (uint32_t)cz * kP2, hz1 = (uint32_t)(cz + 1) * kP2;
    const uint32_t cxu = (uint32_t)cx;

    // batch: issue all 8 gathers, then FMA
    v2f hv[8];
#pragma unroll
    for (int c = 0; c < 8; ++c) {
        const int dx = c & 1, dy = (c >> 1) & 1, dz = (c >> 2) & 1;
        const uint32_t idx =
            ((cxu + (uint32_t)dx) ^ (dy ? hy1 : hy0) ^ (dz ? hz1 : hz0))
            & (kT - 1u);
        hv[c] = *(const v2f*)(tbl + 2u * idx);
    }
    float r0 = 0.0f, r1 = 0.0f;
#pragma unroll
    for (int c = 0; c < 8; ++c) {
        const int dx = c & 1, dy = (c >> 1) & 1, dz = (c >> 2) & 1;
        const float w = (dx ? wx : ux) * (dy ? wy : uy) * (dz ? wz : uz);
        r0 = fmaf(hv[c].x, w, r0);
        r1 = fmaf(hv[c].y, w, r1);
    }
    v2f o; o.x = r0; o.y = r1;
    // full-line coalesced (64 lanes x 8 B contiguous): nt is safe here
    __builtin_nontemporal_store(
        o, (v2f*)(ws + ((size_t)(lv - 5) * n + p) * 2));
}

// ---------- Phase 2: dense recompute + hashed readback -> out[N][32] --------
// MLP-batched: all 31 loads issued before any FMA. Then single-phase LDS
// transpose (32 KB, swizzle r*32 + ((c ^ (r&7))<<2), R6/R7-proven) and
// full-line nt stores.
__global__ __launch_bounds__(256) void gather_out_kernel(
    const float* __restrict__ x, const float* __restrict__ table,
    const float* __restrict__ ws, const float* __restrict__ mask,
    float* __restrict__ out, int n)
{
    __shared__ float lds[256 * 32];             // 32 KB

    const int tid = threadIdx.x;
    const int p   = blockIdx.x * 256 + tid;
    const int pc  = (p < n) ? p : (n - 1);      // clamp: no early return (barrier)

    float px, py, pz;
    load_xyz(x, pc, px, py, pz);

    // ---- load phase: everything in flight, no mask branches ----
    v2f hv[11];
#pragma unroll
    for (int l = 0; l < 11; ++l)
        hv[l] = __builtin_nontemporal_load(
            (const v2f*)(ws + ((size_t)l * n + pc) * 2));

    v4f ab[5][4];
    float wxa[5], wya[5], wza[5];
#pragma unroll
    for (int lv = 0; lv < 5; ++lv) {
        const int res = kRes[lv];
        int cx, cy, cz; float wx, wy, wz;
        corner_setup(px, py, pz, res, cx, cy, cz, wx, wy, wz);
        wxa[lv] = wx; wya[lv] = wy; wza[lv] = wz;
        const float* __restrict__ tbl = table + (size_t)lv * (size_t)(kT * 2);
#pragma unroll
        for (int c = 0; c < 4; ++c) {
            const int dy = c & 1, dz = (c >> 1) & 1;
            const uint32_t idx0 =
                (uint32_t)(cx + res * ((cy + dy) + res * (cz + dz)));
            // entries idx0 and idx0+1 are the two x-corners: one 16 B load
            __builtin_memcpy(&ab[lv][c], tbl + 2u * idx0, sizeof(v4f));
        }
    }

    // ---- FMA phase ----
    v4f o[8];
#pragma unroll
    for (int lv = 0; lv < 5; ++lv) {
        const float m0 = mask[2 * lv], m1 = mask[2 * lv + 1];
        const float wx = wxa[lv], wy = wya[lv], wz = wza[lv];
        const float ux = 1.0f - wx, uy = 1.0f - wy, uz = 1.0f - wz;
        float r0 = 0.0f, r1 = 0.0f;
#pragma unroll
        for (int c = 0; c < 4; ++c) {
            const int dy = c & 1, dz = (c >> 1) & 1;
            const float wyz = (dy ? wy : uy) * (dz ? wz : uz);
            const float w0 = ux * wyz, w1 = wx * wyz;
            r0 = fmaf(ab[lv][c].x, w0, fmaf(ab[lv][c].z, w1, r0));
            r1 = fmaf(ab[lv][c].y, w0, fmaf(ab[lv][c].w, w1, r1));
        }
        r0 *= m0; r1 *= m1;   // dense table data is finite: plain multiply ok
        if (lv & 1) { o[lv >> 1].z = r0; o[lv >> 1].w = r1; }
        else        { o[lv >> 1].x = r0; o[lv >> 1].y = r1; }
    }
#pragma unroll
    for (int lv = 5; lv < kNLevels; ++lv) {
        const float m0 = mask[2 * lv], m1 = mask[2 * lv + 1];
        const bool active = (m0 != 0.0f) || (m1 != 0.0f);
        // ws for masked levels is uninitialized: select, don't multiply
        const float r0 = active ? hv[lv - 5].x * m0 : 0.0f;
        const float r1 = active ? hv[lv - 5].y * m1 : 0.0f;
        if (lv & 1) { o[lv >> 1].z = r0; o[lv >> 1].w = r1; }
        else        { o[lv >> 1].x = r0; o[lv >> 1].y = r1; }
    }

    // ---- single-phase LDS transpose + coalesced full-line nt stores ----
#pragma unroll
    for (int c = 0; c < 8; ++c)
        *(v4f*)&lds[tid * 32 + ((c ^ (tid & 7)) << 2)] = o[c];
    __syncthreads();

    const long long bp = (long long)blockIdx.x * 256;
    float* const obase = out + (size_t)bp * 32;
#pragma unroll
    for (int j = 0; j < 8; ++j) {
        const int m  = tid + 256 * j;           // 16 B chunk id, 0..2047
        const int pr = m >> 3, c = m & 7;
        if (bp + pr < n) {
            const v4f v = *(const v4f*)&lds[pr * 32 + ((c ^ (pr & 7)) << 2)];
            // 64 lanes x 16 B contiguous = full lines: nt safe
            __builtin_nontemporal_store(v, (v4f*)obase + m);
        }
    }
}

// ---------- Fallback (R1 fused kernel) if ws is too small -------------------
__global__ __launch_bounds__(256) void fused_kernel(
    const float* __restrict__ x, const float* __restrict__ table,
    const float* __restrict__ mask, float* __restrict__ out, int n)
{
    const int p = blockIdx.x * blockDim.x + threadIdx.x;
    if (p >= n) return;
    const float px = x[3 * p + 0], py = x[3 * p + 1], pz = x[3 * p + 2];
    v4f o[8];
#pragma unroll
    for (int lv = 0; lv < kNLevels; ++lv) {
        const float m0 = mask[2 * lv], m1 = mask[2 * lv + 1];
        float r0 = 0.0f, r1 = 0.0f;
        if (m0 != 0.0f || m1 != 0.0f) {
            const int res = kRes[lv];
            const bool dense = ((long long)res * res * res) <= (long long)kT;
            int cx, cy, cz; float wx, wy, wz;
            corner_setup(px, py, pz, res, cx, cy, cz, wx, wy, wz);
            const float ux = 1.0f - wx, uy = 1.0f - wy, uz = 1.0f - wz;
            const float* __restrict__ tbl = table + (size_t)lv * (size_t)(kT * 2);
#pragma unroll
            for (int c = 0; c < 8; ++c) {
                const int dx = c & 1, dy = (c >> 1) & 1, dz = (c >> 2) & 1;
                const int ix = cx + dx, iy = cy + dy, iz = cz + dz;
                uint32_t idx;
                if (dense) idx = (uint32_t)(ix + res * (iy + res * iz));
                else idx = (((uint32_t)ix) ^ ((uint32_t)iy * kP1)
                                           ^ ((uint32_t)iz * kP2)) & (kT - 1u);
                const v2f v = *(const v2f*)(tbl + 2u * idx);
                const float w = (dx ? wx : ux) * (dy ? wy : uy) * (dz ? wz : uz);
                r0 = fmaf(v.x, w, r0);
                r1 = fmaf(v.y, w, r1);
            }
            r0 *= m0; r1 *= m1;
        }
        if (lv & 1) { o[lv >> 1].z = r0; o[lv >> 1].w = r1; }
        else        { o[lv >> 1].x = r0; o[lv >> 1].y = r1; }
    }
    v4f* __restrict__ op = (v4f*)(out + (size_t)p * 32);
#pragma unroll
    for (int i = 0; i < 8; ++i) op[i] = o[i];
}

}  // namespace

extern "C" void kernel_launch(void* const* d_in, const int* in_sizes, int n_in,
                              void* d_out, int out_size, void* d_ws, size_t ws_size,
                              hipStream_t stream) {
    const float* x     = (const float*)d_in[0];
    const float* table = (const float*)d_in[1];
    const float* mask  = (const float*)d_in[2];
    float*       out   = (float*)d_out;

    const int n = in_sizes[0] / 3;  // 1048576 points
    const int block = 256;
    const int gx = (n + block - 1) / block;

    const size_t ws_needed = (size_t)(kNLevels - 5) * (size_t)n * 2 * sizeof(float);
    if (ws_size >= ws_needed) {
        float* ws = (float*)d_ws;
        dim3 grid1(gx, kNLevels - 5);   // hashed levels 5..15 as y-slices
        hashed_level_kernel<<<grid1, block, 0, stream>>>(x, table, mask, ws, n);
        gather_out_kernel<<<gx, block, 0, stream>>>(x, table, ws, mask, out, n);
    } else {
        fused_kernel<<<gx, block, 0, stream>>>(x, table, mask, out, n);
    }
}

// Round 4
// 326.279 us; speedup vs baseline: 1.0623x; 1.0623x over previous
//
#include <hip/hip_runtime.h>
#include <cstdint>
#include <cstddef>

// Instant-NGP hash-grid encode, R9.
//
// History: R1 fused 247 us (L2 thrash). R5 split: hashed-slices + gather =
// 350.7 us harness (gather 130.5). R6 LDS-transpose + full-line nt stores:
// 326.0 (gather 106). R7 single-phase flush: 325.1 (gather 101.4; occ 39.6%
// vs R6 70% at same time -> throughput-bound, not latency/occupancy-bound).
// R8 unconditional ws loads: REGRESSION 346.6 (gather 124.6, FETCH 28.8->
// 61.7 MB): levels 8-15 are masked off, loading their ws anyway = 8 extra
// 8 MB streams. Load-batching itself bought ~0 -> confirms pure TA/line-
// throughput regime (~2.7 cyc/CU per 64B line for this mix).
//
// R9: keep batched load->FMA structure, but mask-guard the ws loads again
// (wave-uniform s_cbranch; inactive hv zero-initialized so FMA phase is
// unconditional). Expect gather back to ~100 us, FETCH ~28.9 MB.
//
// Floor accounting (line model): hashed kernel ~90 us (3 active levels x
// 8 random gathers), gather_out ~100 us (20 dense pair-gathers + 11-level
// readback + stores), harness fixed overhead ~130 us.

namespace {

constexpr int      kNLevels = 16;
constexpr uint32_t kT       = 1u << 19;             // 524288 entries / level
constexpr uint32_t kP1      = 2654435761u;           // tcnn hash primes (y, z)
constexpr uint32_t kP2      = 805459861u;

typedef float v2f __attribute__((ext_vector_type(2)));
typedef float v4f __attribute__((ext_vector_type(4)));

// floor(16 * scale^lv) + 1, scale = exp((ln 2048 - ln 16)/15)
__device__ constexpr int kRes[kNLevels] = {
    17, 23, 31, 43, 59, 81, 112, 154, 213, 295, 407, 562, 777, 1073, 1483, 2049
};
// dense iff res^3 <= T  <=>  res <= 80; levels 0..4 dense, 5..15 hashed.

__device__ inline void corner_setup(float px, float py, float pz, int res,
                                    int& cx, int& cy, int& cz,
                                    float& wx, float& wy, float& wz) {
    const float s = (float)(res - 1);
    const float fx = px * s, fy = py * s, fz = pz * s;
    cx = (int)floorf(fx); cy = (int)floorf(fy); cz = (int)floorf(fz);
    cx = min(max(cx, 0), res - 2);
    cy = min(max(cy, 0), res - 2);
    cz = min(max(cz, 0), res - 2);
    wx = fx - (float)cx; wy = fy - (float)cy; wz = fz - (float)cz;
}

__device__ inline void load_xyz(const float* __restrict__ x, int p,
                                float& px, float& py, float& pz) {
    float v[3];
    __builtin_memcpy(v, x + 3 * (size_t)p, 12);   // dwordx2 + dword
    px = v[0]; py = v[1]; pz = v[2];
}

// ---------- Phase 1: hashed levels 5..15, one blockIdx.y slice per level ----
__global__ __launch_bounds__(256) void hashed_level_kernel(
    const float* __restrict__ x, const float* __restrict__ table,
    const float* __restrict__ mask, float* __restrict__ ws, int n)
{
    const int lv = 5 + blockIdx.y;
    const float m0 = mask[2 * lv], m1 = mask[2 * lv + 1];
    if (m0 == 0.0f && m1 == 0.0f) return;   // masked level: slice exits

    const int p = blockIdx.x * blockDim.x + threadIdx.x;
    if (p >= n) return;
    float px, py, pz;
    load_xyz(x, p, px, py, pz);

    const int res = kRes[lv];
    int cx, cy, cz; float wx, wy, wz;
    corner_setup(px, py, pz, res, cx, cy, cz, wx, wy, wz);
    const float ux = 1.0f - wx, uy = 1.0f - wy, uz = 1.0f - wz;
    const float* __restrict__ tbl = table + (size_t)lv * (size_t)(kT * 2);

    // hash components (CSE'd): idx = (cx+dx) ^ hy[dy] ^ hz[dz], masked
    const uint32_t hy0 = (uint32_t)cy * kP1, hy1 = (uint32_t)(cy + 1) * kP1;
    const uint32_t hz0 = (uint32_t)cz * kP2, hz1 = (uint32_t)(cz + 1) * kP2;
    const uint32_t cxu = (uint32_t)cx;

    // batch: issue all 8 gathers, then FMA
    v2f hv[8];
#pragma unroll
    for (int c = 0; c < 8; ++c) {
        const int dx = c & 1, dy = (c >> 1) & 1, dz = (c >> 2) & 1;
        const uint32_t idx =
            ((cxu + (uint32_t)dx) ^ (dy ? hy1 : hy0) ^ (dz ? hz1 : hz0))
            & (kT - 1u);
        hv[c] = *(const v2f*)(tbl + 2u * idx);
    }
    float r0 = 0.0f, r1 = 0.0f;
#pragma unroll
    for (int c = 0; c < 8; ++c) {
        const int dx = c & 1, dy = (c >> 1) & 1, dz = (c >> 2) & 1;
        const float w = (dx ? wx : ux) * (dy ? wy : uy) * (dz ? wz : uz);
        r0 = fmaf(hv[c].x, w, r0);
        r1 = fmaf(hv[c].y, w, r1);
    }
    v2f o; o.x = r0; o.y = r1;
    // full-line coalesced (64 lanes x 8 B contiguous): nt is safe here
    __builtin_nontemporal_store(
        o, (v2f*)(ws + ((size_t)(lv - 5) * n + p) * 2));
}

// ---------- Phase 2: dense recompute + hashed readback -> out[N][32] --------
// Batched load->FMA; ws loads mask-guarded (wave-uniform branch). Then
// single-phase LDS transpose (32 KB, swizzle r*32 + ((c ^ (r&7))<<2),
// R6/R7-proven) and full-line nt stores.
__global__ __launch_bounds__(256) void gather_out_kernel(
    const float* __restrict__ x, const float* __restrict__ table,
    const float* __restrict__ ws, const float* __restrict__ mask,
    float* __restrict__ out, int n)
{
    __shared__ float lds[256 * 32];             // 32 KB

    const int tid = threadIdx.x;
    const int p   = blockIdx.x * 256 + tid;
    const int pc  = (p < n) ? p : (n - 1);      // clamp: no early return (barrier)

    float px, py, pz;
    load_xyz(x, pc, px, py, pz);

    // ---- load phase ----
    // hashed readback: only active levels touch memory (mask is uniform ->
    // scalar branch; levels 8-15 masked off cost nothing, R8 lesson).
    v2f hv[11];
#pragma unroll
    for (int l = 0; l < 11; ++l) {
        hv[l].x = 0.0f; hv[l].y = 0.0f;
        if (mask[2 * (l + 5)] != 0.0f || mask[2 * (l + 5) + 1] != 0.0f)
            hv[l] = __builtin_nontemporal_load(
                (const v2f*)(ws + ((size_t)l * n + pc) * 2));
    }

    // dense levels 0..4: recompute (tables 2.65 MB, chip-wide L2-hot).
    v4f ab[5][4];
    float wxa[5], wya[5], wza[5];
#pragma unroll
    for (int lv = 0; lv < 5; ++lv) {
        const int res = kRes[lv];
        int cx, cy, cz; float wx, wy, wz;
        corner_setup(px, py, pz, res, cx, cy, cz, wx, wy, wz);
        wxa[lv] = wx; wya[lv] = wy; wza[lv] = wz;
        const float* __restrict__ tbl = table + (size_t)lv * (size_t)(kT * 2);
#pragma unroll
        for (int c = 0; c < 4; ++c) {
            const int dy = c & 1, dz = (c >> 1) & 1;
            const uint32_t idx0 =
                (uint32_t)(cx + res * ((cy + dy) + res * (cz + dz)));
            // entries idx0 and idx0+1 are the two x-corners: one 16 B load
            __builtin_memcpy(&ab[lv][c], tbl + 2u * idx0, sizeof(v4f));
        }
    }

    // ---- FMA phase ----
    v4f o[8];
#pragma unroll
    for (int lv = 0; lv < 5; ++lv) {
        const float m0 = mask[2 * lv], m1 = mask[2 * lv + 1];
        const float wx = wxa[lv], wy = wya[lv], wz = wza[lv];
        const float ux = 1.0f - wx, uy = 1.0f - wy, uz = 1.0f - wz;
        float r0 = 0.0f, r1 = 0.0f;
#pragma unroll
        for (int c = 0; c < 4; ++c) {
            const int dy = c & 1, dz = (c >> 1) & 1;
            const float wyz = (dy ? wy : uy) * (dz ? wz : uz);
            const float w0 = ux * wyz, w1 = wx * wyz;
            r0 = fmaf(ab[lv][c].x, w0, fmaf(ab[lv][c].z, w1, r0));
            r1 = fmaf(ab[lv][c].y, w0, fmaf(ab[lv][c].w, w1, r1));
        }
        r0 *= m0; r1 *= m1;   // dense table data is finite: plain multiply ok
        if (lv & 1) { o[lv >> 1].z = r0; o[lv >> 1].w = r1; }
        else        { o[lv >> 1].x = r0; o[lv >> 1].y = r1; }
    }
#pragma unroll
    for (int lv = 5; lv < kNLevels; ++lv) {
        const float m0 = mask[2 * lv], m1 = mask[2 * lv + 1];
        // hv is 0 for inactive levels: plain multiply, no NaN leak
        const float r0 = hv[lv - 5].x * m0;
        const float r1 = hv[lv - 5].y * m1;
        if (lv & 1) { o[lv >> 1].z = r0; o[lv >> 1].w = r1; }
        else        { o[lv >> 1].x = r0; o[lv >> 1].y = r1; }
    }

    // ---- single-phase LDS transpose + coalesced full-line nt stores ----
#pragma unroll
    for (int c = 0; c < 8; ++c)
        *(v4f*)&lds[tid * 32 + ((c ^ (tid & 7)) << 2)] = o[c];
    __syncthreads();

    const long long bp = (long long)blockIdx.x * 256;
    float* const obase = out + (size_t)bp * 32;
#pragma unroll
    for (int j = 0; j < 8; ++j) {
        const int m  = tid + 256 * j;           // 16 B chunk id, 0..2047
        const int pr = m >> 3, c = m & 7;
        if (bp + pr < n) {
            const v4f v = *(const v4f*)&lds[pr * 32 + ((c ^ (pr & 7)) << 2)];
            // 64 lanes x 16 B contiguous = full lines: nt safe
            __builtin_nontemporal_store(v, (v4f*)obase + m);
        }
    }
}

// ---------- Fallback (R1 fused kernel) if ws is too small -------------------
__global__ __launch_bounds__(256) void fused_kernel(
    const float* __restrict__ x, const float* __restrict__ table,
    const float* __restrict__ mask, float* __restrict__ out, int n)
{
    const int p = blockIdx.x * blockDim.x + threadIdx.x;
    if (p >= n) return;
    const float px = x[3 * p + 0], py = x[3 * p + 1], pz = x[3 * p + 2];
    v4f o[8];
#pragma unroll
    for (int lv = 0; lv < kNLevels; ++lv) {
        const float m0 = mask[2 * lv], m1 = mask[2 * lv + 1];
        float r0 = 0.0f, r1 = 0.0f;
        if (m0 != 0.0f || m1 != 0.0f) {
            const int res = kRes[lv];
            const bool dense = ((long long)res * res * res) <= (long long)kT;
            int cx, cy, cz; float wx, wy, wz;
            corner_setup(px, py, pz, res, cx, cy, cz, wx, wy, wz);
            const float ux = 1.0f - wx, uy = 1.0f - wy, uz = 1.0f - wz;
            const float* __restrict__ tbl = table + (size_t)lv * (size_t)(kT * 2);
#pragma unroll
            for (int c = 0; c < 8; ++c) {
                const int dx = c & 1, dy = (c >> 1) & 1, dz = (c >> 2) & 1;
                const int ix = cx + dx, iy = cy + dy, iz = cz + dz;
                uint32_t idx;
                if (dense) idx = (uint32_t)(ix + res * (iy + res * iz));
                else idx = (((uint32_t)ix) ^ ((uint32_t)iy * kP1)
                                           ^ ((uint32_t)iz * kP2)) & (kT - 1u);
                const v2f v = *(const v2f*)(tbl + 2u * idx);
                const float w = (dx ? wx : ux) * (dy ? wy : uy) * (dz ? wz : uz);
                r0 = fmaf(v.x, w, r0);
                r1 = fmaf(v.y, w, r1);
            }
            r0 *= m0; r1 *= m1;
        }
        if (lv & 1) { o[lv >> 1].z = r0; o[lv >> 1].w = r1; }
        else        { o[lv >> 1].x = r0; o[lv >> 1].y = r1; }
    }
    v4f* __restrict__ op = (v4f*)(out + (size_t)p * 32);
#pragma unroll
    for (int i = 0; i < 8; ++i) op[i] = o[i];
}

}  // namespace

extern "C" void kernel_launch(void* const* d_in, const int* in_sizes, int n_in,
                              void* d_out, int out_size, void* d_ws, size_t ws_size,
                              hipStream_t stream) {
    const float* x     = (const float*)d_in[0];
    const float* table = (const float*)d_in[1];
    const float* mask  = (const float*)d_in[2];
    float*       out   = (float*)d_out;

    const int n = in_sizes[0] / 3;  // 1048576 points
    const int block = 256;
    const int gx = (n + block - 1) / block;

    const size_t ws_needed = (size_t)(kNLevels - 5) * (size_t)n * 2 * sizeof(float);
    if (ws_size >= ws_needed) {
        float* ws = (float*)d_ws;
        dim3 grid1(gx, kNLevels - 5);   // hashed levels 5..15 as y-slices
        hashed_level_kernel<<<grid1, block, 0, stream>>>(x, table, mask, ws, n);
        gather_out_kernel<<<gx, block, 0, stream>>>(x, table, ws, mask, out, n);
    } else {
        fused_kernel<<<gx, block, 0, stream>>>(x, table, mask, out, n);
    }
}